// Round 1
// baseline (1436.272 us; speedup 1.0000x reference)
//
#include <hip/hip_runtime.h>

// Problem constants (B=8, N=4096, n_points=1024, n_samples=32, D_PTS=6, MLPS=[64,64,128])
#define NPTS  4096
#define NB    8
#define NC    1024
#define NSAMP 32
#define DP    6
#define C0    9      // 3 + D_PTS
#define C3    128
#define ROWS_TOT 262144   // NB*NC*NSAMP

// Workspace layout (bytes). Requires ws_size >= ~208 MB.
#define OFF_SS   (32ull*1024ull)                 // scale/shift: 3 layers x 256 floats
#define OFF_PART (64ull*1024ull)                 // stats partials: 256 blk x 2 x 128 floats
#define OFF_H0   (1ull<<20)                      // h0: 262144 x 9 f32   (9.4 MB)
#define OFF_Y0   (16ull<<20)                     // y0: 262144 x 64 f32  (67 MB)
#define OFF_Y2   (16ull<<20)                     // y2 reuses y0 region  (134 MB; y0 dead)
#define OFF_Y1   (OFF_Y2 + 134217728ull)         // y1: 262144 x 64 f32  (67 MB) @ 151 MB

// Exact (no-FMA) squared distance to match numpy rounding; sum order ((x+y)+z).
__device__ __forceinline__ float sqdist_noc(float x, float y, float z,
                                            float cx, float cy, float cz) {
  #pragma clang fp contract(off)
  float dx = x - cx, dy = y - cy, dz = z - cz;
  return dx * dx + dy * dy + dz * dz;
}

// ---------------------------------------------------------------------------
// FPS: greedy farthest-from-last selection, 1023 sequential steps per batch.
// argmax tie-break = first index, via packed key (dist_bits<<12)|(4095-idx).
// Writes cent_xyz (output 0) directly.
// ---------------------------------------------------------------------------
__global__ __launch_bounds__(256)
void fps_kernel(const float* __restrict__ xyz, float* __restrict__ cent) {
  const int b = blockIdx.x;
  const int t = threadIdx.x;
  const float* X = xyz + (size_t)b * NPTS * 3;
  float* OC = cent + (size_t)b * NC * 3;

  __shared__ float sxyz[NPTS * 3];
  __shared__ unsigned long long wk[4];
  __shared__ int ssel;

  for (int e = t; e < NPTS * 3; e += 256) sxyz[e] = X[e];
  __syncthreads();

  float px[16], py[16], pz[16];
  #pragma unroll
  for (int i = 0; i < 16; i++) {
    int j = t * 16 + i;
    px[i] = sxyz[j * 3 + 0];
    py[i] = sxyz[j * 3 + 1];
    pz[i] = sxyz[j * 3 + 2];
  }

  int last = 0;  // deterministic seed index 0
  for (int k = 1; k < NC; k++) {
    float cx = sxyz[last * 3 + 0];
    float cy = sxyz[last * 3 + 1];
    float cz = sxyz[last * 3 + 2];
    if (t == 0) {  // emit centroid coords for selection k-1
      OC[(k - 1) * 3 + 0] = cx;
      OC[(k - 1) * 3 + 1] = cy;
      OC[(k - 1) * 3 + 2] = cz;
    }
    if ((last >> 4) == t) {  // retire `last`: poison -> never wins a > compare
      int ii = last & 15;
      #pragma unroll
      for (int i = 0; i < 16; i++)
        if (i == ii) px[i] = __int_as_float(0x7FC00000);
    }

    float mx = -1.0f; int mj = -1;
    #pragma unroll
    for (int i = 0; i < 16; i++) {
      float sq = sqdist_noc(px[i], py[i], pz[i], cx, cy, cz);
      if (sq > mx) { mx = sq; mj = t * 16 + i; }   // strict > keeps first index
    }
    unsigned long long key = 0ull;
    if (mj >= 0) {
      float d = (mx > 0.f) ? sqrtf(mx) : 0.f;      // safe_norm, IEEE sqrt
      key = ((unsigned long long)__float_as_uint(d) << 12) |
            (unsigned long long)(4095 - mj);       // tie -> smaller index wins
    }
    #pragma unroll
    for (int off = 32; off; off >>= 1) {
      unsigned long long o = __shfl_xor(key, off);
      if (o > key) key = o;
    }
    if ((t & 63) == 0) wk[t >> 6] = key;
    __syncthreads();
    if (t == 0) {
      unsigned long long m = wk[0];
      if (wk[1] > m) m = wk[1];
      if (wk[2] > m) m = wk[2];
      if (wk[3] > m) m = wk[3];
      ssel = 4095 - (int)(m & 0xFFFull);
    }
    __syncthreads();
    last = ssel;
  }
  if (t == 0) {
    OC[(NC - 1) * 3 + 0] = sxyz[last * 3 + 0];
    OC[(NC - 1) * 3 + 1] = sxyz[last * 3 + 1];
    OC[(NC - 1) * 3 + 2] = sxyz[last * 3 + 2];
  }
}

// ---------------------------------------------------------------------------
// query_ball + gather + concat: stable argsort(min(dist,0.04))[:32] ==
// 32 smallest by (dist, idx). One block per centroid; 32 min-reduction rounds
// over per-thread register keys. Writes h0[centroid][32][9].
// ---------------------------------------------------------------------------
__global__ __launch_bounds__(256)
void ball_kernel(const float* __restrict__ xyz, const float* __restrict__ pts,
                 const float* __restrict__ cent, float* __restrict__ h0) {
  const int blk = blockIdx.x;       // b*NC + c
  const int b = blk >> 10;
  const int t = threadIdx.x;
  const float* X = xyz + (size_t)b * NPTS * 3;
  const float* P = pts + (size_t)b * NPTS * DP;
  const float cx = cent[(size_t)blk * 3 + 0];
  const float cy = cent[(size_t)blk * 3 + 1];
  const float cz = cent[(size_t)blk * 3 + 2];

  unsigned long long key[16];
  #pragma unroll
  for (int i = 0; i < 16; i++) {
    int j = t * 16 + i;
    float sq = sqdist_noc(X[j * 3 + 0], X[j * 3 + 1], X[j * 3 + 2], cx, cy, cz);
    float d = (sq > 0.f) ? sqrtf(sq) : 0.f;
    d = fminf(d, 0.04f);            // source quirk: norm vs radius^2
    key[i] = ((unsigned long long)__float_as_uint(d) << 12) |
             (unsigned long long)j;
  }

  __shared__ unsigned long long wk[4];
  __shared__ int sel[NSAMP];
  __shared__ int sbc;
  for (int k = 0; k < NSAMP; k++) {
    unsigned long long best = ~0ull;
    #pragma unroll
    for (int i = 0; i < 16; i++)
      if (key[i] < best) best = key[i];
    #pragma unroll
    for (int off = 32; off; off >>= 1) {
      unsigned long long o = __shfl_xor(best, off);
      if (o < best) best = o;
    }
    if ((t & 63) == 0) wk[t >> 6] = best;
    __syncthreads();
    if (t == 0) {
      unsigned long long m = wk[0];
      if (wk[1] < m) m = wk[1];
      if (wk[2] < m) m = wk[2];
      if (wk[3] < m) m = wk[3];
      int j = (int)(m & 0xFFFull);
      sel[k] = j; sbc = j;
    }
    __syncthreads();
    int j = sbc;
    if ((j >> 4) == t) {            // retire selected point (compile-time idx)
      int ii = j & 15;
      #pragma unroll
      for (int i = 0; i < 16; i++)
        if (i == ii) key[i] = ~0ull;
    }
  }
  // gather + concat -> h0 (sel[] visible: written before last barrier)
  float* H = h0 + (size_t)blk * NSAMP * C0;
  for (int e = t; e < NSAMP * C0; e += 256) {
    int k = e / C0;
    int c = e - k * C0;
    int j = sel[k];
    H[e] = (c < 3) ? X[j * 3 + c] : P[j * DP + (c - 3)];
  }
}

// ---------------------------------------------------------------------------
// dense0: h0[262144,9] @ W[9,64] + b -> y0 (raw, pre-BN). 64 rows/block.
// ---------------------------------------------------------------------------
__global__ __launch_bounds__(256)
void dense0_kernel(const float* __restrict__ h0, const float* __restrict__ W,
                   const float* __restrict__ bias, float* __restrict__ yout) {
  __shared__ float xs[64 * C0];
  __shared__ float ws[C0 * 64];
  const int blk = blockIdx.x, t = threadIdx.x;
  const size_t rbase = (size_t)blk * 64;
  for (int e = t; e < 64 * C0; e += 256) xs[e] = h0[rbase * C0 + e];
  for (int e = t; e < C0 * 64; e += 256) ws[e] = W[e];
  __syncthreads();
  const int rg = t >> 4, cg = t & 15;      // 16 row-groups x 16 ch-groups (x4 each)
  float acc[4][4];
  float4 bv = *(const float4*)(bias + cg * 4);
  #pragma unroll
  for (int r = 0; r < 4; r++) { acc[r][0] = bv.x; acc[r][1] = bv.y; acc[r][2] = bv.z; acc[r][3] = bv.w; }
  #pragma unroll
  for (int k = 0; k < C0; k++) {
    float4 wv = *(const float4*)(ws + k * 64 + cg * 4);
    #pragma unroll
    for (int r = 0; r < 4; r++) {
      float x = xs[(rg * 4 + r) * C0 + k];
      acc[r][0] = fmaf(x, wv.x, acc[r][0]);
      acc[r][1] = fmaf(x, wv.y, acc[r][1]);
      acc[r][2] = fmaf(x, wv.z, acc[r][2]);
      acc[r][3] = fmaf(x, wv.w, acc[r][3]);
    }
  }
  #pragma unroll
  for (int r = 0; r < 4; r++)
    *(float4*)(yout + (rbase + rg * 4 + r) * 64 + cg * 4) =
        make_float4(acc[r][0], acc[r][1], acc[r][2], acc[r][3]);
}

// ---------------------------------------------------------------------------
// dense mid: x = relu(yin*scale+shift) (prev layer's BN fused on load),
// y = x @ W[64,COUT] + b. RPB rows/block, 4 rows x 4 ch per thread.
// ---------------------------------------------------------------------------
template <int RPB, int COUT, int CGN>
__global__ __launch_bounds__(256)
void dense_mid_kernel(const float* __restrict__ yin, const float* __restrict__ ssin,
                      const float* __restrict__ W, const float* __restrict__ bias,
                      float* __restrict__ yout) {
  __shared__ float xs[RPB * 68];      // pad 64 -> 68 (bank spread, keeps f4 align)
  __shared__ float ws[64 * COUT];
  __shared__ float scs[64], shs[64];
  const int blk = blockIdx.x, t = threadIdx.x;
  if (t < 64) { scs[t] = ssin[t]; shs[t] = ssin[128 + t]; }
  __syncthreads();
  const size_t rbase = (size_t)blk * RPB;
  for (int e = t; e < RPB * 64; e += 256) {
    int c = e & 63;
    float v = yin[rbase * 64 + e];
    xs[(e >> 6) * 68 + c] = fmaxf(fmaf(v, scs[c], shs[c]), 0.f);
  }
  for (int e = t; e < 64 * COUT; e += 256) ws[e] = W[e];
  __syncthreads();
  const int rg = t / CGN, cg = t % CGN;
  float acc[4][4];
  float4 bv = *(const float4*)(bias + cg * 4);
  #pragma unroll
  for (int r = 0; r < 4; r++) { acc[r][0] = bv.x; acc[r][1] = bv.y; acc[r][2] = bv.z; acc[r][3] = bv.w; }
  for (int k0 = 0; k0 < 64; k0 += 4) {
    float4 xv[4];
    #pragma unroll
    for (int r = 0; r < 4; r++)
      xv[r] = *(const float4*)(xs + (rg * 4 + r) * 68 + k0);
    #pragma unroll
    for (int kk = 0; kk < 4; kk++) {
      float4 wv = *(const float4*)(ws + (k0 + kk) * COUT + cg * 4);
      #pragma unroll
      for (int r = 0; r < 4; r++) {
        float x = (&xv[r].x)[kk];
        acc[r][0] = fmaf(x, wv.x, acc[r][0]);
        acc[r][1] = fmaf(x, wv.y, acc[r][1]);
        acc[r][2] = fmaf(x, wv.z, acc[r][2]);
        acc[r][3] = fmaf(x, wv.w, acc[r][3]);
      }
    }
  }
  #pragma unroll
  for (int r = 0; r < 4; r++)
    *(float4*)(yout + (rbase + rg * 4 + r) * COUT + cg * 4) =
        make_float4(acc[r][0], acc[r][1], acc[r][2], acc[r][3]);
}

// ---------------------------------------------------------------------------
// BN stats, stage 1: deterministic per-block channel sum/sumsq partials.
// 256 blocks x 1024 rows each; fully coalesced (addr = base + i*256 + t).
// ---------------------------------------------------------------------------
template <int C>
__global__ __launch_bounds__(256)
void stats_kernel(const float* __restrict__ y, float* __restrict__ part) {
  const int t = threadIdx.x, blk = blockIdx.x;
  const size_t base = (size_t)blk * 1024 * C;
  float s = 0.f, q = 0.f;
  const int iters = 1024 * C / 256;
  for (int i = 0; i < iters; i++) {
    float v = y[base + (size_t)i * 256 + t];
    s += v;
    q = fmaf(v, v, q);
  }
  __shared__ float ss[256], qs[256];
  ss[t] = s; qs[t] = q;
  __syncthreads();
  if (t < C) {   // channel of thread t is t%C; fixed order -> deterministic
    float S = 0.f, Q = 0.f;
    for (int j = t; j < 256; j += C) { S += ss[j]; Q += qs[j]; }
    part[(size_t)blk * 2 * C + t] = S;
    part[(size_t)blk * 2 * C + C + t] = Q;
  }
}

// BN stats, stage 2: fold partials -> scale = g*rsqrt(var+eps), shift = be - mean*scale
__global__ void stats_final_kernel(const float* __restrict__ part,
                                   const float* __restrict__ g,
                                   const float* __restrict__ be,
                                   float* __restrict__ ss_out, int C) {
  const int c = threadIdx.x;
  if (c >= C) return;
  float S = 0.f, Q = 0.f;
  for (int b2 = 0; b2 < 256; b2++) {
    S += part[(size_t)b2 * 2 * C + c];
    Q += part[(size_t)b2 * 2 * C + C + c];
  }
  const float inv = 1.0f / 262144.0f;
  float mean = S * inv;
  float var = Q * inv - mean * mean;
  float scale = g[c] / sqrtf(var + 1e-3f);
  ss_out[c] = scale;
  ss_out[128 + c] = be[c] - mean * scale;
}

// max over 32 samples of relu(affine(y2)) -> output 1
__global__ __launch_bounds__(128)
void pool_kernel(const float* __restrict__ y2, const float* __restrict__ ss2,
                 float* __restrict__ out1) {
  const int blk = blockIdx.x, c = threadIdx.x;
  const float sc = ss2[c], sh = ss2[128 + c];
  const float* Y = y2 + (size_t)blk * NSAMP * C3 + c;
  float m = -3.4e38f;
  #pragma unroll 4
  for (int s = 0; s < NSAMP; s++) m = fmaxf(m, fmaf(Y[s * C3], sc, sh));
  out1[(size_t)blk * C3 + c] = fmaxf(m, 0.f);
}

extern "C" void kernel_launch(void* const* d_in, const int* in_sizes, int n_in,
                              void* d_out, int out_size, void* d_ws, size_t ws_size,
                              hipStream_t stream) {
  const float* xyz = (const float*)d_in[0];
  const float* pts = (const float*)d_in[1];
  const float* w0 = (const float*)d_in[2];
  const float* b0 = (const float*)d_in[3];
  const float* g0 = (const float*)d_in[4];
  const float* be0 = (const float*)d_in[5];
  const float* w1 = (const float*)d_in[6];
  const float* b1 = (const float*)d_in[7];
  const float* g1 = (const float*)d_in[8];
  const float* be1 = (const float*)d_in[9];
  const float* w2 = (const float*)d_in[10];
  const float* b2 = (const float*)d_in[11];
  const float* g2 = (const float*)d_in[12];
  const float* be2 = (const float*)d_in[13];

  float* out = (float*)d_out;
  float* cent = out;                       // [8,1024,3]
  float* out1 = out + (size_t)NB * NC * 3; // [8,1024,128]

  char* ws = (char*)d_ws;
  float* ssA  = (float*)(ws + OFF_SS);     // 3 x {scale[128], shift[128]}
  float* part = (float*)(ws + OFF_PART);
  float* h0   = (float*)(ws + OFF_H0);
  float* y0   = (float*)(ws + OFF_Y0);
  float* y1   = (float*)(ws + OFF_Y1);
  float* y2   = (float*)(ws + OFF_Y2);     // reuses y0 region (y0 dead by then)

  fps_kernel<<<dim3(NB), dim3(256), 0, stream>>>(xyz, cent);
  ball_kernel<<<dim3(NB * NC), dim3(256), 0, stream>>>(xyz, pts, cent, h0);

  dense0_kernel<<<dim3(ROWS_TOT / 64), dim3(256), 0, stream>>>(h0, w0, b0, y0);
  stats_kernel<64><<<dim3(256), dim3(256), 0, stream>>>(y0, part);
  stats_final_kernel<<<dim3(1), dim3(128), 0, stream>>>(part, g0, be0, ssA + 0 * 256, 64);

  dense_mid_kernel<64, 64, 16><<<dim3(ROWS_TOT / 64), dim3(256), 0, stream>>>(y0, ssA + 0 * 256, w1, b1, y1);
  stats_kernel<64><<<dim3(256), dim3(256), 0, stream>>>(y1, part);
  stats_final_kernel<<<dim3(1), dim3(128), 0, stream>>>(part, g1, be1, ssA + 1 * 256, 64);

  dense_mid_kernel<32, 128, 32><<<dim3(ROWS_TOT / 32), dim3(256), 0, stream>>>(y1, ssA + 1 * 256, w2, b2, y2);
  stats_kernel<128><<<dim3(256), dim3(256), 0, stream>>>(y2, part);
  stats_final_kernel<<<dim3(1), dim3(128), 0, stream>>>(part, g2, be2, ssA + 2 * 256, 128);

  pool_kernel<<<dim3(NB * NC), dim3(128), 0, stream>>>(y2, ssA + 2 * 256, out1);

  (void)in_sizes; (void)n_in; (void)out_size; (void)ws_size;
}

// Round 2
// 1351.852 us; speedup vs baseline: 1.0624x; 1.0624x over previous
//
#include <hip/hip_runtime.h>

// Problem constants (B=8, N=4096, n_points=1024, n_samples=32, D_PTS=6, MLPS=[64,64,128])
#define NPTS  4096
#define NB    8
#define NC    1024
#define NSAMP 32
#define DP    6
#define C0    9      // 3 + D_PTS
#define C3    128
#define ROWS_TOT 262144   // NB*NC*NSAMP

// Workspace layout (bytes). Requires ws_size >= ~184 MB.
#define OFF_SS   (32ull<<10)     // 3 layers x {scale[128], shift[128]}
#define OFF_H0   (1ull<<20)      // h0: 262144 x 9 f32 (9.4 MB)
#define OFF_Y0   (16ull<<20)     // y0: 262144 x 64 f32 (67 MB)
#define OFF_Y1   (96ull<<20)     // y1: 262144 x 64 f32 (67 MB)
#define OFF_PSUM (168ull<<20)    // per-block channel sums   [C][NBLK] (max 4 MB)
#define OFF_PSQ  (172ull<<20)    // per-block channel sumsq  [C][NBLK] (max 4 MB)
#define OFF_GMX  (176ull<<20)    // per-centroid channel max [8192][128] (4 MB)
#define OFF_GMN  (180ull<<20)    // per-centroid channel min [8192][128] (4 MB)

// Exact (no-FMA) squared distance to match numpy rounding; sum order ((x+y)+z).
__device__ __forceinline__ float sqdist_noc(float x, float y, float z,
                                            float cx, float cy, float cz) {
  #pragma clang fp contract(off)
  float dx = x - cx, dy = y - cy, dz = z - cz;
  return dx * dx + dy * dy + dz * dz;
}

// ---------------------------------------------------------------------------
// FPS: 1023 sequential farthest-from-last steps. Latency-optimized:
// ONE barrier per step; wave leaders publish 64-bit keys to parity-buffered
// wk[2][4]; every thread redundantly folds the 4 keys (no t0 serial section,
// no broadcast round-trip). Centroid fetch = one ds_read_b128.
// argmax tie-break = first index via key (dist_bits<<12)|(4095-idx).
// ---------------------------------------------------------------------------
__global__ __launch_bounds__(256)
void fps_kernel(const float* __restrict__ xyz, float* __restrict__ cent) {
  const int b = blockIdx.x;
  const int t = threadIdx.x;
  const float* X = xyz + (size_t)b * NPTS * 3;
  float* OC = cent + (size_t)b * NC * 3;

  __shared__ float4 sxyz[NPTS];                 // 64 KB, padded for b128 reads
  __shared__ unsigned long long wk[2][4];

  for (int p = t; p < NPTS; p += 256)
    sxyz[p] = make_float4(X[p * 3 + 0], X[p * 3 + 1], X[p * 3 + 2], 0.f);
  __syncthreads();

  float px[16], py[16], pz[16];
  #pragma unroll
  for (int i = 0; i < 16; i++) {
    float4 v = sxyz[t * 16 + i];
    px[i] = v.x; py[i] = v.y; pz[i] = v.z;
  }

  int last = 0;  // deterministic seed index 0
  for (int k = 1; k < NC; k++) {
    float4 c = sxyz[last];
    if (t == 0) {  // emit centroid coords for selection k-1 (off critical path)
      OC[(k - 1) * 3 + 0] = c.x;
      OC[(k - 1) * 3 + 1] = c.y;
      OC[(k - 1) * 3 + 2] = c.z;
    }
    if ((last >> 4) == t) {  // retire `last`: NaN loses every > compare
      int ii = last & 15;
      #pragma unroll
      for (int i = 0; i < 16; i++)
        if (i == ii) px[i] = __int_as_float(0x7FC00000);
    }

    float mx = -1.0f; int mj = 0;
    #pragma unroll
    for (int i = 0; i < 16; i++) {
      float sq = sqdist_noc(px[i], py[i], pz[i], c.x, c.y, c.z);
      if (sq > mx) { mx = sq; mj = i; }          // strict > keeps first index
    }
    float d = (mx > 0.f) ? sqrtf(mx) : 0.f;      // safe_norm, IEEE sqrt
    unsigned long long key =
        ((unsigned long long)__float_as_uint(d) << 12) |
        (unsigned long long)(4095 - (t * 16 + mj));  // tie -> smaller idx wins
    #pragma unroll
    for (int off = 32; off; off >>= 1) {
      unsigned long long o = __shfl_xor(key, off);
      if (o > key) key = o;
    }
    const int par = k & 1;
    if ((t & 63) == 0) wk[par][t >> 6] = key;
    __syncthreads();
    unsigned long long m0 = wk[par][0], m1 = wk[par][1];
    unsigned long long m2 = wk[par][2], m3 = wk[par][3];
    if (m1 > m0) m0 = m1;
    if (m3 > m2) m2 = m3;
    if (m2 > m0) m0 = m2;
    last = 4095 - (int)(m0 & 0xFFFull);
  }
  if (t == 0) {
    float4 c = sxyz[last];
    OC[(NC - 1) * 3 + 0] = c.x;
    OC[(NC - 1) * 3 + 1] = c.y;
    OC[(NC - 1) * 3 + 2] = c.z;
  }
}

// ---------------------------------------------------------------------------
// query_ball + gather + concat: stable argsort(min(dist,0.04))[:32] ==
// 32 smallest by (dist, idx). One block per centroid; 32 min rounds with the
// same one-barrier parity scheme. Writes h0[centroid][32][9].
// ---------------------------------------------------------------------------
__global__ __launch_bounds__(256)
void ball_kernel(const float* __restrict__ xyz, const float* __restrict__ pts,
                 const float* __restrict__ cent, float* __restrict__ h0) {
  const int blk = blockIdx.x;       // b*NC + c
  const int b = blk >> 10;
  const int t = threadIdx.x;
  const float* X = xyz + (size_t)b * NPTS * 3;
  const float* P = pts + (size_t)b * NPTS * DP;
  const float cx = cent[(size_t)blk * 3 + 0];
  const float cy = cent[(size_t)blk * 3 + 1];
  const float cz = cent[(size_t)blk * 3 + 2];

  unsigned long long key[16];
  #pragma unroll
  for (int i = 0; i < 16; i++) {
    int j = t * 16 + i;
    float sq = sqdist_noc(X[j * 3 + 0], X[j * 3 + 1], X[j * 3 + 2], cx, cy, cz);
    float d = (sq > 0.f) ? sqrtf(sq) : 0.f;
    d = fminf(d, 0.04f);            // source quirk: norm vs radius^2
    key[i] = ((unsigned long long)__float_as_uint(d) << 12) |
             (unsigned long long)j;
  }

  __shared__ unsigned long long wk[2][4];
  __shared__ int sel[NSAMP];
  for (int k = 0; k < NSAMP; k++) {
    unsigned long long best = ~0ull;
    #pragma unroll
    for (int i = 0; i < 16; i++)
      if (key[i] < best) best = key[i];
    #pragma unroll
    for (int off = 32; off; off >>= 1) {
      unsigned long long o = __shfl_xor(best, off);
      if (o < best) best = o;
    }
    const int par = k & 1;
    if ((t & 63) == 0) wk[par][t >> 6] = best;
    __syncthreads();
    unsigned long long m0 = wk[par][0], m1 = wk[par][1];
    unsigned long long m2 = wk[par][2], m3 = wk[par][3];
    if (m1 < m0) m0 = m1;
    if (m3 < m2) m2 = m3;
    if (m2 < m0) m0 = m2;
    int j = (int)(m0 & 0xFFFull);
    if (t == 0) sel[k] = j;
    if ((j >> 4) == t) {            // retire selected point
      int ii = j & 15;
      #pragma unroll
      for (int i = 0; i < 16; i++)
        if (i == ii) key[i] = ~0ull;
    }
  }
  __syncthreads();
  // gather + concat -> h0
  float* H = h0 + (size_t)blk * NSAMP * C0;
  for (int e = t; e < NSAMP * C0; e += 256) {
    int k = e / C0;
    int c = e - k * C0;
    int j = sel[k];
    H[e] = (c < 3) ? X[j * 3 + c] : P[j * DP + (c - 3)];
  }
}

// ---------------------------------------------------------------------------
// dense0: h0[262144,9] @ W[9,64] + b -> y0, with fused deterministic BN
// partials (per-block channel sum/sumsq). 64 rows/block, 4096 blocks.
// ---------------------------------------------------------------------------
__global__ __launch_bounds__(256)
void dense0_kernel(const float* __restrict__ h0, const float* __restrict__ W,
                   const float* __restrict__ bias, float* __restrict__ yout,
                   float* __restrict__ psum, float* __restrict__ psq) {
  __shared__ float xs[64 * C0];
  __shared__ float ws[C0 * 64];
  __shared__ float red[2][16][64];
  const int blk = blockIdx.x, t = threadIdx.x;
  const size_t rbase = (size_t)blk * 64;
  for (int e = t; e < 64 * C0; e += 256) xs[e] = h0[rbase * C0 + e];
  for (int e = t; e < C0 * 64; e += 256) ws[e] = W[e];
  __syncthreads();
  const int rg = t >> 4, cg = t & 15;
  float acc[4][4];
  float4 bv = *(const float4*)(bias + cg * 4);
  #pragma unroll
  for (int r = 0; r < 4; r++) { acc[r][0] = bv.x; acc[r][1] = bv.y; acc[r][2] = bv.z; acc[r][3] = bv.w; }
  #pragma unroll
  for (int k = 0; k < C0; k++) {
    float4 wv = *(const float4*)(ws + k * 64 + cg * 4);
    #pragma unroll
    for (int r = 0; r < 4; r++) {
      float x = xs[(rg * 4 + r) * C0 + k];
      acc[r][0] = fmaf(x, wv.x, acc[r][0]);
      acc[r][1] = fmaf(x, wv.y, acc[r][1]);
      acc[r][2] = fmaf(x, wv.z, acc[r][2]);
      acc[r][3] = fmaf(x, wv.w, acc[r][3]);
    }
  }
  #pragma unroll
  for (int r = 0; r < 4; r++)
    *(float4*)(yout + (rbase + rg * 4 + r) * 64 + cg * 4) =
        make_float4(acc[r][0], acc[r][1], acc[r][2], acc[r][3]);
  // fused BN partials
  #pragma unroll
  for (int c4 = 0; c4 < 4; c4++) {
    float s = 0.f, q = 0.f;
    #pragma unroll
    for (int r = 0; r < 4; r++) { float v = acc[r][c4]; s += v; q = fmaf(v, v, q); }
    red[0][rg][cg * 4 + c4] = s;
    red[1][rg][cg * 4 + c4] = q;
  }
  __syncthreads();
  if (t < 64) {
    float S = 0.f, Q = 0.f;
    #pragma unroll
    for (int g = 0; g < 16; g++) { S += red[0][g][t]; Q += red[1][g][t]; }
    psum[(size_t)t * 4096 + blk] = S;
    psq [(size_t)t * 4096 + blk] = Q;
  }
}

// ---------------------------------------------------------------------------
// dense mid: x = relu(yin*scale+shift) fused on load, y = x @ W[64,COUT] + b,
// fused BN partials; optionally (MM) per-block (=per-centroid) max/min of raw
// y instead of materializing y at all (layer 2).
// ---------------------------------------------------------------------------
template <int RPB, int COUT, int CGN, int NBLKS, bool MM>
__global__ __launch_bounds__(256)
void dense_mid_kernel(const float* __restrict__ yin, const float* __restrict__ ssin,
                      const float* __restrict__ W, const float* __restrict__ bias,
                      float* __restrict__ yout,
                      float* __restrict__ psum, float* __restrict__ psq,
                      float* __restrict__ gmax, float* __restrict__ gmin) {
  constexpr int NG = 256 / CGN;        // row-groups (of 4 rows) per block
  __shared__ float xs[RPB * 68];       // pad 64 -> 68 (keeps 16B align: 272B rows)
  __shared__ float ws[64 * COUT];
  __shared__ float scs[64], shs[64];
  __shared__ float red[2][NG][COUT];
  __shared__ float redm[MM ? 2 : 1][MM ? NG : 1][MM ? COUT : 1];
  const int blk = blockIdx.x, t = threadIdx.x;
  if (t < 64) { scs[t] = ssin[t]; shs[t] = ssin[128 + t]; }
  __syncthreads();
  const size_t rbase = (size_t)blk * RPB;
  for (int e = t; e < RPB * 64; e += 256) {
    int c = e & 63;
    float v = yin[rbase * 64 + e];
    xs[(e >> 6) * 68 + c] = fmaxf(fmaf(v, scs[c], shs[c]), 0.f);
  }
  for (int e = t; e < 64 * COUT; e += 256) ws[e] = W[e];
  __syncthreads();
  const int rg = t / CGN, cg = t % CGN;
  float acc[4][4];
  float4 bv = *(const float4*)(bias + cg * 4);
  #pragma unroll
  for (int r = 0; r < 4; r++) { acc[r][0] = bv.x; acc[r][1] = bv.y; acc[r][2] = bv.z; acc[r][3] = bv.w; }
  for (int k0 = 0; k0 < 64; k0 += 4) {
    float4 xv[4];
    #pragma unroll
    for (int r = 0; r < 4; r++)
      xv[r] = *(const float4*)(xs + (rg * 4 + r) * 68 + k0);
    #pragma unroll
    for (int kk = 0; kk < 4; kk++) {
      float4 wv = *(const float4*)(ws + (k0 + kk) * COUT + cg * 4);
      #pragma unroll
      for (int r = 0; r < 4; r++) {
        float x = (&xv[r].x)[kk];
        acc[r][0] = fmaf(x, wv.x, acc[r][0]);
        acc[r][1] = fmaf(x, wv.y, acc[r][1]);
        acc[r][2] = fmaf(x, wv.z, acc[r][2]);
        acc[r][3] = fmaf(x, wv.w, acc[r][3]);
      }
    }
  }
  if constexpr (!MM) {
    #pragma unroll
    for (int r = 0; r < 4; r++)
      *(float4*)(yout + (rbase + rg * 4 + r) * COUT + cg * 4) =
          make_float4(acc[r][0], acc[r][1], acc[r][2], acc[r][3]);
  }
  #pragma unroll
  for (int c4 = 0; c4 < 4; c4++) {
    float s = 0.f, q = 0.f;
    #pragma unroll
    for (int r = 0; r < 4; r++) { float v = acc[r][c4]; s += v; q = fmaf(v, v, q); }
    red[0][rg][cg * 4 + c4] = s;
    red[1][rg][cg * 4 + c4] = q;
    if constexpr (MM) {
      float mx = acc[0][c4], mn = acc[0][c4];
      #pragma unroll
      for (int r = 1; r < 4; r++) { mx = fmaxf(mx, acc[r][c4]); mn = fminf(mn, acc[r][c4]); }
      redm[0][rg][cg * 4 + c4] = mx;
      redm[1][rg][cg * 4 + c4] = mn;
    }
  }
  __syncthreads();
  if (t < COUT) {
    float S = 0.f, Q = 0.f;
    #pragma unroll
    for (int g = 0; g < NG; g++) { S += red[0][g][t]; Q += red[1][g][t]; }
    psum[(size_t)t * NBLKS + blk] = S;
    psq [(size_t)t * NBLKS + blk] = Q;
    if constexpr (MM) {
      float mx = redm[0][0][t], mn = redm[1][0][t];
      #pragma unroll
      for (int g = 1; g < NG; g++) { mx = fmaxf(mx, redm[0][g][t]); mn = fminf(mn, redm[1][g][t]); }
      gmax[(size_t)blk * COUT + t] = mx;   // [blk][ch] for coalesced pool read
      gmin[(size_t)blk * COUT + t] = mn;
    }
  }
}

// ---------------------------------------------------------------------------
// stats finalize: per channel, fold NBLK partials -> scale/shift.
// grid = C blocks x 256 threads; deterministic fixed-order reduction.
// ---------------------------------------------------------------------------
template <int NBLK>
__global__ __launch_bounds__(256)
void stats_final_kernel(const float* __restrict__ psum, const float* __restrict__ psq,
                        const float* __restrict__ g, const float* __restrict__ be,
                        float* __restrict__ ss_out) {
  const int c = blockIdx.x, t = threadIdx.x;
  float S = 0.f, Q = 0.f;
  for (int i = t; i < NBLK; i += 256) {
    S += psum[(size_t)c * NBLK + i];
    Q += psq [(size_t)c * NBLK + i];
  }
  __shared__ float sS[256], sQ[256];
  sS[t] = S; sQ[t] = Q;
  __syncthreads();
  #pragma unroll
  for (int off = 128; off; off >>= 1) {
    if (t < off) { sS[t] += sS[t + off]; sQ[t] += sQ[t + off]; }
    __syncthreads();
  }
  if (t == 0) {
    const float inv = 1.0f / 262144.0f;
    float mean = sS[0] * inv;
    float var = sQ[0] * inv - mean * mean;
    float scale = g[c] / sqrtf(var + 1e-3f);
    ss_out[c] = scale;
    ss_out[128 + c] = be[c] - mean * scale;
  }
}

// pool finalize: out1[cent][ch] = relu(sc*(sc>=0?max:min)+sh)
__global__ __launch_bounds__(128)
void pool_final_kernel(const float* __restrict__ gmax, const float* __restrict__ gmin,
                       const float* __restrict__ ss2, float* __restrict__ out1) {
  const int blk = blockIdx.x, c = threadIdx.x;
  const float sc = ss2[c], sh = ss2[128 + c];
  float v = (sc >= 0.f) ? gmax[(size_t)blk * C3 + c] : gmin[(size_t)blk * C3 + c];
  out1[(size_t)blk * C3 + c] = fmaxf(fmaf(v, sc, sh), 0.f);
}

extern "C" void kernel_launch(void* const* d_in, const int* in_sizes, int n_in,
                              void* d_out, int out_size, void* d_ws, size_t ws_size,
                              hipStream_t stream) {
  const float* xyz = (const float*)d_in[0];
  const float* pts = (const float*)d_in[1];
  const float* w0 = (const float*)d_in[2];
  const float* b0 = (const float*)d_in[3];
  const float* g0 = (const float*)d_in[4];
  const float* be0 = (const float*)d_in[5];
  const float* w1 = (const float*)d_in[6];
  const float* b1 = (const float*)d_in[7];
  const float* g1 = (const float*)d_in[8];
  const float* be1 = (const float*)d_in[9];
  const float* w2 = (const float*)d_in[10];
  const float* b2 = (const float*)d_in[11];
  const float* g2 = (const float*)d_in[12];
  const float* be2 = (const float*)d_in[13];

  float* out = (float*)d_out;
  float* cent = out;                       // [8,1024,3]
  float* out1 = out + (size_t)NB * NC * 3; // [8,1024,128]

  char* ws = (char*)d_ws;
  float* ssA  = (float*)(ws + OFF_SS);
  float* h0   = (float*)(ws + OFF_H0);
  float* y0   = (float*)(ws + OFF_Y0);
  float* y1   = (float*)(ws + OFF_Y1);
  float* psum = (float*)(ws + OFF_PSUM);
  float* psq  = (float*)(ws + OFF_PSQ);
  float* gmx  = (float*)(ws + OFF_GMX);
  float* gmn  = (float*)(ws + OFF_GMN);

  fps_kernel<<<dim3(NB), dim3(256), 0, stream>>>(xyz, cent);
  ball_kernel<<<dim3(NB * NC), dim3(256), 0, stream>>>(xyz, pts, cent, h0);

  dense0_kernel<<<dim3(ROWS_TOT / 64), dim3(256), 0, stream>>>(h0, w0, b0, y0, psum, psq);
  stats_final_kernel<4096><<<dim3(64), dim3(256), 0, stream>>>(psum, psq, g0, be0, ssA + 0 * 256);

  dense_mid_kernel<64, 64, 16, 4096, false><<<dim3(ROWS_TOT / 64), dim3(256), 0, stream>>>(
      y0, ssA + 0 * 256, w1, b1, y1, psum, psq, nullptr, nullptr);
  stats_final_kernel<4096><<<dim3(64), dim3(256), 0, stream>>>(psum, psq, g1, be1, ssA + 1 * 256);

  dense_mid_kernel<32, 128, 32, 8192, true><<<dim3(ROWS_TOT / 32), dim3(256), 0, stream>>>(
      y1, ssA + 1 * 256, w2, b2, nullptr, psum, psq, gmx, gmn);
  stats_final_kernel<8192><<<dim3(128), dim3(256), 0, stream>>>(psum, psq, g2, be2, ssA + 2 * 256);

  pool_final_kernel<<<dim3(NB * NC), dim3(128), 0, stream>>>(gmx, gmn, ssA + 2 * 256, out1);

  (void)in_sizes; (void)n_in; (void)out_size; (void)ws_size;
}

// Round 3
// 1087.248 us; speedup vs baseline: 1.3210x; 1.2434x over previous
//
#include <hip/hip_runtime.h>

// Problem constants (B=8, N=4096, n_points=1024, n_samples=32, D_PTS=6, MLPS=[64,64,128])
#define NPTS  4096
#define NB    8
#define NC    1024
#define NSAMP 32
#define DP    6
#define C0    9      // 3 + D_PTS
#define C3    128
#define ROWS_TOT 262144   // NB*NC*NSAMP

// Workspace layout (bytes). Requires ws_size >= ~184 MB.
#define OFF_SS   (32ull<<10)     // 3 layers x {scale[128], shift[128]}
#define OFF_H0   (1ull<<20)      // h0: 262144 x 9 f32 (9.4 MB)
#define OFF_Y0   (16ull<<20)     // y0: 262144 x 64 f32 (67 MB)
#define OFF_Y1   (96ull<<20)     // y1: 262144 x 64 f32 (67 MB)
#define OFF_PSUM (168ull<<20)    // per-block channel sums   [C][NBLK] (max 4 MB)
#define OFF_PSQ  (172ull<<20)    // per-block channel sumsq  [C][NBLK] (max 4 MB)
#define OFF_GMX  (176ull<<20)    // per-centroid channel max [8192][128] (4 MB)
#define OFF_GMN  (180ull<<20)    // per-centroid channel min [8192][128] (4 MB)

typedef unsigned long long ull;

// Exact (no-FMA) squared distance to match numpy rounding; sum order ((x+y)+z).
__device__ __forceinline__ float sqdist_noc(float x, float y, float z,
                                            float cx, float cy, float cz) {
  #pragma clang fp contract(off)
  float dx = x - cx, dy = y - cy, dz = z - cz;
  return dx * dx + dy * dy + dz * dz;
}

// DPP move with old=self (masked/invalid lanes keep their value -> fmax identity)
template <int CTRL, int RM>
__device__ __forceinline__ float dpp_mov_f(float x) {
  int xi = __float_as_int(x);
  int r = __builtin_amdgcn_update_dpp(xi, xi, CTRL, RM, 0xf, false);
  return __int_as_float(r);
}

// Canonical gfx9-style wave64 max reduce; result valid in lane 63. VALU-speed.
__device__ __forceinline__ float wave64_fmax(float x) {
  x = fmaxf(x, dpp_mov_f<0x111, 0xf>(x));  // row_shr:1
  x = fmaxf(x, dpp_mov_f<0x112, 0xf>(x));  // row_shr:2
  x = fmaxf(x, dpp_mov_f<0x114, 0xf>(x));  // row_shr:4
  x = fmaxf(x, dpp_mov_f<0x118, 0xf>(x));  // row_shr:8
  x = fmaxf(x, dpp_mov_f<0x142, 0xa>(x));  // row_bcast:15 -> rows 1,3
  x = fmaxf(x, dpp_mov_f<0x143, 0xc>(x));  // row_bcast:31 -> rows 2,3
  return x;
}

__device__ __forceinline__ ull umax64(ull a, ull b) { return a > b ? a : b; }

// ---------------------------------------------------------------------------
// FPS: 1023 sequential farthest-from-last steps. 512 threads, 8 pts/thread.
// Per step: local argmax (8) -> DPP wave max (VALU pipe, no LDS) -> ballot+
// readlane index (lane order == index order -> first-index tie-break) ->
// 8 leader keys in parity LDS -> 1 barrier -> all threads fold 8 keys.
// Selection compares squared distance (monotone w/ sqrt; tie-break by index).
// ---------------------------------------------------------------------------
__global__ __launch_bounds__(512)
void fps_kernel(const float* __restrict__ xyz, float* __restrict__ cent) {
  const int b = blockIdx.x;
  const int t = threadIdx.x;
  const float* X = xyz + (size_t)b * NPTS * 3;
  float* OC = cent + (size_t)b * NC * 3;

  __shared__ float4 sxyz[NPTS];                 // 64 KB
  __shared__ alignas(16) ull wk[2][8];

  for (int p = t; p < NPTS; p += 512)
    sxyz[p] = make_float4(X[p * 3 + 0], X[p * 3 + 1], X[p * 3 + 2], 0.f);
  __syncthreads();

  float px[8], py[8], pz[8];
  #pragma unroll
  for (int i = 0; i < 8; i++) {
    float4 v = sxyz[t * 8 + i];
    px[i] = v.x; py[i] = v.y; pz[i] = v.z;
  }

  int last = 0;  // deterministic seed index 0
  for (int k = 1; k < NC; k++) {
    const int par = k & 1;
    float4 c = sxyz[last];                      // broadcast read
    if (t == 0) {                               // emit centroid k-1
      OC[(k - 1) * 3 + 0] = c.x;
      OC[(k - 1) * 3 + 1] = c.y;
      OC[(k - 1) * 3 + 2] = c.z;
    }
    if ((last >> 3) == t) {                     // retire: NaN loses all compares
      int ii = last & 7;
      #pragma unroll
      for (int i = 0; i < 8; i++)
        if (i == ii) px[i] = __int_as_float(0x7FC00000);
    }

    float mx = -1.0f; int mj = 0;
    #pragma unroll
    for (int i = 0; i < 8; i++) {
      float sq = sqdist_noc(px[i], py[i], pz[i], c.x, c.y, c.z);
      if (sq > mx) { mx = sq; mj = i; }         // strict > keeps first index
    }
    int gidx = t * 8 + mj;

    float wm = wave64_fmax(mx);
    int smax = __builtin_amdgcn_readlane(__float_as_int(wm), 63);
    ull bal = __ballot(__float_as_int(mx) == smax);
    if (bal == 0ull) bal = 1ull;                // paranoia (shouldn't happen)
    int fl = __ffsll(bal) - 1;                  // first lane = first index
    int widx = __builtin_amdgcn_readlane(gidx, fl);

    if ((t & 63) == 0) {
      ull key = ((ull)(unsigned)smax << 12) | (unsigned)(4095 - widx);
      if (smax < 0) key = 0;                    // degenerate wave never wins
      wk[par][t >> 6] = key;
    }
    __syncthreads();
    const ulonglong2* W2 = (const ulonglong2*)&wk[par][0];
    ulonglong2 p0 = W2[0], p1 = W2[1], p2 = W2[2], p3 = W2[3];
    ull m0 = umax64(umax64(p0.x, p0.y), umax64(p1.x, p1.y));
    ull m1 = umax64(umax64(p2.x, p2.y), umax64(p3.x, p3.y));
    last = 4095 - (int)(umax64(m0, m1) & 0xFFFull);
  }
  if (t == 0) {
    float4 c = sxyz[last];
    OC[(NC - 1) * 3 + 0] = c.x;
    OC[(NC - 1) * 3 + 1] = c.y;
    OC[(NC - 1) * 3 + 2] = c.z;
  }
}

// ---------------------------------------------------------------------------
// query_ball + gather + concat, exact stable-argsort semantics via the
// min(dist, r^2=0.04) quirk: points with d >= 0.04 all tie -> stable sort
// emits them in ascending index order. So: compact "inner" points
// (d = sqrt(sq) < 0.04, guard sq < 0.0017), rank-sort them (order-independent
// -> deterministic despite atomics), fill the rest with ascending non-inner
// indices. Centroid itself is always inner (d=0).
// ---------------------------------------------------------------------------
#define BCAP 256
__global__ __launch_bounds__(256)
void ball_kernel(const float* __restrict__ xyz, const float* __restrict__ pts,
                 const float* __restrict__ cent, float* __restrict__ h0) {
  const int blk = blockIdx.x;       // b*NC + c
  const int b = blk >> 10;
  const int t = threadIdx.x;
  const float* X = xyz + (size_t)b * NPTS * 3;
  const float* P = pts + (size_t)b * NPTS * DP;
  const float cx = cent[(size_t)blk * 3 + 0];
  const float cy = cent[(size_t)blk * 3 + 1];
  const float cz = cent[(size_t)blk * 3 + 2];

  __shared__ int scount;
  __shared__ ull skeys[BCAP];
  __shared__ ull ssorted[BCAP];
  __shared__ int sel[NSAMP];
  if (t == 0) scount = 0;
  __syncthreads();

  #pragma unroll
  for (int i = 0; i < 16; i++) {
    int j = t * 16 + i;
    float sq = sqdist_noc(X[j * 3 + 0], X[j * 3 + 1], X[j * 3 + 2], cx, cy, cz);
    if (sq < 0.0017f) {                       // conservative guard
      float d = (sq > 0.f) ? sqrtf(sq) : 0.f; // exact per-reference norm
      if (d < 0.04f) {                        // strictly inside the clip value
        int pos = atomicAdd(&scount, 1);
        if (pos < BCAP)
          skeys[pos] = ((ull)(unsigned)__float_as_int(d) << 12) | (unsigned)j;
      }
    }
  }
  __syncthreads();
  const int M = min(scount, BCAP);

  // rank-sort the inner set (all keys distinct: idx embedded)
  if (t < M) {
    ull my = skeys[t];
    int r = 0;
    for (int j2 = 0; j2 < M; j2++) r += (skeys[j2] < my);
    ssorted[r] = my;
  }
  __syncthreads();

  if (t < NSAMP) {
    int v;
    if (t < M) {
      v = (int)(ssorted[t] & 0xFFFull);
    } else {
      // s-th smallest index NOT in the inner set
      int s = t - M;
      int idx = s;
      for (int it = 0; it < 40; it++) {
        int c = 0;
        for (int j2 = 0; j2 < M; j2++) c += ((int)(skeys[j2] & 0xFFFull) <= idx);
        int nidx = s + c;
        if (nidx == idx) break;
        idx = nidx;
      }
      v = idx;
    }
    sel[t] = v;
  }
  __syncthreads();

  // gather + concat -> h0
  float* H = h0 + (size_t)blk * NSAMP * C0;
  for (int e = t; e < NSAMP * C0; e += 256) {
    int k = e / C0;
    int c = e - k * C0;
    int j = sel[k];
    H[e] = (c < 3) ? X[j * 3 + c] : P[j * DP + (c - 3)];
  }
}

// ---------------------------------------------------------------------------
// dense0: h0[262144,9] @ W[9,64] + b -> y0, with fused deterministic BN
// partials (per-block channel sum/sumsq). 64 rows/block, 4096 blocks.
// ---------------------------------------------------------------------------
__global__ __launch_bounds__(256)
void dense0_kernel(const float* __restrict__ h0, const float* __restrict__ W,
                   const float* __restrict__ bias, float* __restrict__ yout,
                   float* __restrict__ psum, float* __restrict__ psq) {
  __shared__ float xs[64 * C0];
  __shared__ float ws[C0 * 64];
  __shared__ float red[2][16][64];
  const int blk = blockIdx.x, t = threadIdx.x;
  const size_t rbase = (size_t)blk * 64;
  for (int e = t; e < 64 * C0; e += 256) xs[e] = h0[rbase * C0 + e];
  for (int e = t; e < C0 * 64; e += 256) ws[e] = W[e];
  __syncthreads();
  const int rg = t >> 4, cg = t & 15;
  float acc[4][4];
  float4 bv = *(const float4*)(bias + cg * 4);
  #pragma unroll
  for (int r = 0; r < 4; r++) { acc[r][0] = bv.x; acc[r][1] = bv.y; acc[r][2] = bv.z; acc[r][3] = bv.w; }
  #pragma unroll
  for (int k = 0; k < C0; k++) {
    float4 wv = *(const float4*)(ws + k * 64 + cg * 4);
    #pragma unroll
    for (int r = 0; r < 4; r++) {
      float x = xs[(rg * 4 + r) * C0 + k];
      acc[r][0] = fmaf(x, wv.x, acc[r][0]);
      acc[r][1] = fmaf(x, wv.y, acc[r][1]);
      acc[r][2] = fmaf(x, wv.z, acc[r][2]);
      acc[r][3] = fmaf(x, wv.w, acc[r][3]);
    }
  }
  #pragma unroll
  for (int r = 0; r < 4; r++)
    *(float4*)(yout + (rbase + rg * 4 + r) * 64 + cg * 4) =
        make_float4(acc[r][0], acc[r][1], acc[r][2], acc[r][3]);
  #pragma unroll
  for (int c4 = 0; c4 < 4; c4++) {
    float s = 0.f, q = 0.f;
    #pragma unroll
    for (int r = 0; r < 4; r++) { float v = acc[r][c4]; s += v; q = fmaf(v, v, q); }
    red[0][rg][cg * 4 + c4] = s;
    red[1][rg][cg * 4 + c4] = q;
  }
  __syncthreads();
  if (t < 64) {
    float S = 0.f, Q = 0.f;
    #pragma unroll
    for (int g = 0; g < 16; g++) { S += red[0][g][t]; Q += red[1][g][t]; }
    psum[(size_t)t * 4096 + blk] = S;
    psq [(size_t)t * 4096 + blk] = Q;
  }
}

// ---------------------------------------------------------------------------
// dense mid: x = relu(yin*scale+shift) fused on load, y = x @ W[64,COUT] + b,
// fused BN partials; optionally (MM) per-block (=per-centroid) max/min of raw
// y instead of materializing y at all (layer 2).
// ---------------------------------------------------------------------------
template <int RPB, int COUT, int CGN, int NBLKS, bool MM>
__global__ __launch_bounds__(256)
void dense_mid_kernel(const float* __restrict__ yin, const float* __restrict__ ssin,
                      const float* __restrict__ W, const float* __restrict__ bias,
                      float* __restrict__ yout,
                      float* __restrict__ psum, float* __restrict__ psq,
                      float* __restrict__ gmax, float* __restrict__ gmin) {
  constexpr int NG = 256 / CGN;
  __shared__ float xs[RPB * 68];
  __shared__ float ws[64 * COUT];
  __shared__ float scs[64], shs[64];
  __shared__ float red[2][NG][COUT];
  __shared__ float redm[MM ? 2 : 1][MM ? NG : 1][MM ? COUT : 1];
  const int blk = blockIdx.x, t = threadIdx.x;
  if (t < 64) { scs[t] = ssin[t]; shs[t] = ssin[128 + t]; }
  __syncthreads();
  const size_t rbase = (size_t)blk * RPB;
  for (int e = t; e < RPB * 64; e += 256) {
    int c = e & 63;
    float v = yin[rbase * 64 + e];
    xs[(e >> 6) * 68 + c] = fmaxf(fmaf(v, scs[c], shs[c]), 0.f);
  }
  for (int e = t; e < 64 * COUT; e += 256) ws[e] = W[e];
  __syncthreads();
  const int rg = t / CGN, cg = t % CGN;
  float acc[4][4];
  float4 bv = *(const float4*)(bias + cg * 4);
  #pragma unroll
  for (int r = 0; r < 4; r++) { acc[r][0] = bv.x; acc[r][1] = bv.y; acc[r][2] = bv.z; acc[r][3] = bv.w; }
  for (int k0 = 0; k0 < 64; k0 += 4) {
    float4 xv[4];
    #pragma unroll
    for (int r = 0; r < 4; r++)
      xv[r] = *(const float4*)(xs + (rg * 4 + r) * 68 + k0);
    #pragma unroll
    for (int kk = 0; kk < 4; kk++) {
      float4 wv = *(const float4*)(ws + (k0 + kk) * COUT + cg * 4);
      #pragma unroll
      for (int r = 0; r < 4; r++) {
        float x = (&xv[r].x)[kk];
        acc[r][0] = fmaf(x, wv.x, acc[r][0]);
        acc[r][1] = fmaf(x, wv.y, acc[r][1]);
        acc[r][2] = fmaf(x, wv.z, acc[r][2]);
        acc[r][3] = fmaf(x, wv.w, acc[r][3]);
      }
    }
  }
  if constexpr (!MM) {
    #pragma unroll
    for (int r = 0; r < 4; r++)
      *(float4*)(yout + (rbase + rg * 4 + r) * COUT + cg * 4) =
          make_float4(acc[r][0], acc[r][1], acc[r][2], acc[r][3]);
  }
  #pragma unroll
  for (int c4 = 0; c4 < 4; c4++) {
    float s = 0.f, q = 0.f;
    #pragma unroll
    for (int r = 0; r < 4; r++) { float v = acc[r][c4]; s += v; q = fmaf(v, v, q); }
    red[0][rg][cg * 4 + c4] = s;
    red[1][rg][cg * 4 + c4] = q;
    if constexpr (MM) {
      float mx = acc[0][c4], mn = acc[0][c4];
      #pragma unroll
      for (int r = 1; r < 4; r++) { mx = fmaxf(mx, acc[r][c4]); mn = fminf(mn, acc[r][c4]); }
      redm[0][rg][cg * 4 + c4] = mx;
      redm[1][rg][cg * 4 + c4] = mn;
    }
  }
  __syncthreads();
  if (t < COUT) {
    float S = 0.f, Q = 0.f;
    #pragma unroll
    for (int g = 0; g < NG; g++) { S += red[0][g][t]; Q += red[1][g][t]; }
    psum[(size_t)t * NBLKS + blk] = S;
    psq [(size_t)t * NBLKS + blk] = Q;
    if constexpr (MM) {
      float mx = redm[0][0][t], mn = redm[1][0][t];
      #pragma unroll
      for (int g = 1; g < NG; g++) { mx = fmaxf(mx, redm[0][g][t]); mn = fminf(mn, redm[1][g][t]); }
      gmax[(size_t)blk * COUT + t] = mx;
      gmin[(size_t)blk * COUT + t] = mn;
    }
  }
}

// ---------------------------------------------------------------------------
// stats finalize: per channel, fold NBLK partials -> scale/shift.
// ---------------------------------------------------------------------------
template <int NBLK>
__global__ __launch_bounds__(256)
void stats_final_kernel(const float* __restrict__ psum, const float* __restrict__ psq,
                        const float* __restrict__ g, const float* __restrict__ be,
                        float* __restrict__ ss_out) {
  const int c = blockIdx.x, t = threadIdx.x;
  float S = 0.f, Q = 0.f;
  for (int i = t; i < NBLK; i += 256) {
    S += psum[(size_t)c * NBLK + i];
    Q += psq [(size_t)c * NBLK + i];
  }
  __shared__ float sS[256], sQ[256];
  sS[t] = S; sQ[t] = Q;
  __syncthreads();
  #pragma unroll
  for (int off = 128; off; off >>= 1) {
    if (t < off) { sS[t] += sS[t + off]; sQ[t] += sQ[t + off]; }
    __syncthreads();
  }
  if (t == 0) {
    const float inv = 1.0f / 262144.0f;
    float mean = sS[0] * inv;
    float var = sQ[0] * inv - mean * mean;
    float scale = g[c] / sqrtf(var + 1e-3f);
    ss_out[c] = scale;
    ss_out[128 + c] = be[c] - mean * scale;
  }
}

// pool finalize: out1[cent][ch] = relu(sc*(sc>=0?max:min)+sh)
__global__ __launch_bounds__(128)
void pool_final_kernel(const float* __restrict__ gmax, const float* __restrict__ gmin,
                       const float* __restrict__ ss2, float* __restrict__ out1) {
  const int blk = blockIdx.x, c = threadIdx.x;
  const float sc = ss2[c], sh = ss2[128 + c];
  float v = (sc >= 0.f) ? gmax[(size_t)blk * C3 + c] : gmin[(size_t)blk * C3 + c];
  out1[(size_t)blk * C3 + c] = fmaxf(fmaf(v, sc, sh), 0.f);
}

extern "C" void kernel_launch(void* const* d_in, const int* in_sizes, int n_in,
                              void* d_out, int out_size, void* d_ws, size_t ws_size,
                              hipStream_t stream) {
  const float* xyz = (const float*)d_in[0];
  const float* pts = (const float*)d_in[1];
  const float* w0 = (const float*)d_in[2];
  const float* b0 = (const float*)d_in[3];
  const float* g0 = (const float*)d_in[4];
  const float* be0 = (const float*)d_in[5];
  const float* w1 = (const float*)d_in[6];
  const float* b1 = (const float*)d_in[7];
  const float* g1 = (const float*)d_in[8];
  const float* be1 = (const float*)d_in[9];
  const float* w2 = (const float*)d_in[10];
  const float* b2 = (const float*)d_in[11];
  const float* g2 = (const float*)d_in[12];
  const float* be2 = (const float*)d_in[13];

  float* out = (float*)d_out;
  float* cent = out;                       // [8,1024,3]
  float* out1 = out + (size_t)NB * NC * 3; // [8,1024,128]

  char* ws = (char*)d_ws;
  float* ssA  = (float*)(ws + OFF_SS);
  float* h0   = (float*)(ws + OFF_H0);
  float* y0   = (float*)(ws + OFF_Y0);
  float* y1   = (float*)(ws + OFF_Y1);
  float* psum = (float*)(ws + OFF_PSUM);
  float* psq  = (float*)(ws + OFF_PSQ);
  float* gmx  = (float*)(ws + OFF_GMX);
  float* gmn  = (float*)(ws + OFF_GMN);

  fps_kernel<<<dim3(NB), dim3(512), 0, stream>>>(xyz, cent);
  ball_kernel<<<dim3(NB * NC), dim3(256), 0, stream>>>(xyz, pts, cent, h0);

  dense0_kernel<<<dim3(ROWS_TOT / 64), dim3(256), 0, stream>>>(h0, w0, b0, y0, psum, psq);
  stats_final_kernel<4096><<<dim3(64), dim3(256), 0, stream>>>(psum, psq, g0, be0, ssA + 0 * 256);

  dense_mid_kernel<64, 64, 16, 4096, false><<<dim3(ROWS_TOT / 64), dim3(256), 0, stream>>>(
      y0, ssA + 0 * 256, w1, b1, y1, psum, psq, nullptr, nullptr);
  stats_final_kernel<4096><<<dim3(64), dim3(256), 0, stream>>>(psum, psq, g1, be1, ssA + 1 * 256);

  dense_mid_kernel<32, 128, 32, 8192, true><<<dim3(ROWS_TOT / 32), dim3(256), 0, stream>>>(
      y1, ssA + 1 * 256, w2, b2, nullptr, psum, psq, gmx, gmn);
  stats_final_kernel<8192><<<dim3(128), dim3(256), 0, stream>>>(psum, psq, g2, be2, ssA + 2 * 256);

  pool_final_kernel<<<dim3(NB * NC), dim3(128), 0, stream>>>(gmx, gmn, ssA + 2 * 256, out1);

  (void)in_sizes; (void)n_in; (void)out_size; (void)ws_size;
}